// Round 8
// baseline (221.446 us; speedup 1.0000x reference)
//
#include <hip/hip_runtime.h>
#include <math.h>

#define NB 8
#define NN 150
#define NE 299          // 2*N-1
#define NNODE (NB*NN)   // 1200

struct Quat { float w, x, y, z; };

__device__ inline Quat qmul(Quat a, Quat b) {
    Quat r;
    r.w = a.w*b.w - a.x*b.x - a.y*b.y - a.z*b.z;
    r.x = a.w*b.x + a.x*b.w + a.y*b.z - a.z*b.y;
    r.y = a.w*b.y - a.x*b.z + a.y*b.w + a.z*b.x;
    r.z = a.w*b.z + a.x*b.y - a.y*b.x + a.z*b.w;
    return r;
}
__device__ inline Quat qconj(Quat a) { return Quat{a.w, -a.x, -a.y, -a.z}; }

__device__ inline float3 qrot(Quat q, float3 v) {
    float tx = 2.f*(q.y*v.z - q.z*v.y);
    float ty = 2.f*(q.z*v.x - q.x*v.z);
    float tz = 2.f*(q.x*v.y - q.y*v.x);
    float cx = q.y*tz - q.z*ty;
    float cy = q.z*tx - q.x*tz;
    float cz = q.x*ty - q.y*tx;
    float3 r;
    r.x = v.x + q.w*tx + cx;
    r.y = v.y + q.w*ty + cy;
    r.z = v.z + q.w*tz + cz;
    return r;
}

// 16-row LDS-transpose reduce pass: after sMat rows are written, sum each
// channel over 192 cols into sPr[4*ch+quarter]. Caller totals + barrier.
__device__ __forceinline__ void reduce_pass(const float* sMat, float* sPr,
                                            int tid, int nch) {
    __syncthreads();
    if (tid < 4*nch) {
        const int ch = tid >> 2, q4i = tid & 3;
        const float4* row = (const float4*)(sMat + ch*196 + q4i*48);
        float s0=0.f, s1=0.f, s2=0.f, s3=0.f;
#pragma unroll
        for (int it = 0; it < 12; ++it) {
            const float4 r = row[it];
            s0 += r.x; s1 += r.y; s2 += r.z; s3 += r.w;
        }
        sPr[tid] = (s0+s1) + (s2+s3);
    }
    __syncthreads();
}

// ---------------------------------------------------------------------------
// P1: layer 1 fully in-block (no init dispatch).
//   Cd_j = h_j @ WmCq (WmCq = WmC@Wq staged, 30x6), Ed inline (192 FMA),
//   Hsum/Etot via LDS reduce passes; msum = 149A_i + (Hsum@WmC - C_i)
//   + (Etot - E149) + Gsum.WmG. Tail: L2 node work + L2 tables.
// ---------------------------------------------------------------------------
struct Pair1Args {
    const float* quats; const float* trans; const float* feats; const int* tptr;
    const float* wm1; const float* bm1; const float* wq1; const float* bq1;
    const float* wf1; const float* bf1;
    const float* wmN; const float* bmN; const float* wqN; const float* bqN;
    float* hout; float* Aout; float* Adout; float* Cout; float* Cdout;
    float* PN; float* EdN; float* GqN;
    float* qout; float* xout;
};

__global__ __launch_bounds__(192, 4) void pair1_kernel(Pair1Args a)
{
    constexpr int STR = 196;
    __shared__ __align__(16) float sMat[16*STR];
    __shared__ float sPr[64];
    __shared__ float sTot[16], sHsum[30], sEt[32];
    __shared__ float sHi[30], sA[32], sCi[32], sAd[6];
    __shared__ float sWq[192], sWmCq[180], sGq[54];
    __shared__ float sMs[32], sO[64], sH2[64], sA2[32], sC2[32];

    const int tid   = threadIdx.x;
    const int nodeI = blockIdx.x;
    const int b     = nodeI / NN;
    const int i     = nodeI - b*NN;
    const int j     = tid;
    const float tval = (float)a.tptr[0] * (1.0f/1000.0f);

    // stage raw
    sWq[tid] = a.wq1[tid];
    if (tid < 30) {
        float v;
        if      (tid < 4)  v = a.quats[nodeI*4 + tid];
        else if (tid < 7)  v = a.trans[nodeI*3 + (tid-4)];
        else if (tid < 29) v = a.feats[nodeI*22 + (tid-7)];
        else               v = tval;
        sHi[tid] = v;
    }
    __syncthreads();   // B0

    // WmCq = WmC@Wq (30x6), Gq = geomrows@Wq (9x6), A_i/C_i
    if (tid < 180) {
        const int d = tid/6, dd = tid - d*6;
        float acc = 0.f;
#pragma unroll
        for (int k = 0; k < 32; ++k) acc = fmaf(a.wm1[(30+d)*32 + k], sWq[k*6+dd], acc);
        sWmCq[tid] = acc;
    }
    if (tid < 54) {
        const int t = tid/6, dd = tid - t*6;
        float acc = 0.f;
#pragma unroll
        for (int k = 0; k < 32; ++k) acc = fmaf(a.wm1[(60+NE+t)*32 + k], sWq[k*6+dd], acc);
        sGq[tid] = acc;
    }
    if (tid >= 128) {
        const int t2 = tid - 128;
        const int k = t2 & 31;
        const int off = (t2 < 32) ? 0 : 30;
        float acc = (t2 < 32) ? a.bm1[k] : 0.f;
#pragma unroll
        for (int d = 0; d < 30; ++d) acc = fmaf(sHi[d], a.wm1[(off+d)*32 + k], acc);
        if (t2 < 32) sA[k] = acc; else sCi[k] = acc;
    }
    __syncthreads();   // B1
    if (tid < 6) {
        float acc = a.bq1[tid];
#pragma unroll
        for (int k = 0; k < 32; ++k) acc = fmaf(sA[k], sWq[k*6+tid], acc);
        sAd[tid] = acc;
    }
    __syncthreads();   // B2

    const float4 qi4 = ((const float4*)a.quats)[nodeI];
    const Quat  qi = {qi4.x, qi4.y, qi4.z, qi4.w};
    const float3 xi = {sHi[4], sHi[5], sHi[6]};

    const bool act = (j < NN);
    const int nodeJ = b*NN + j;
    const float mm = (j == i) ? 0.f : 1.f;

    float hj[30];
    float vals[16];
#pragma unroll
    for (int v = 0; v < 16; ++v) vals[v] = 0.f;

    if (act) {
        const float4 q4 = ((const float4*)a.quats)[nodeJ];
        hj[0]=q4.x; hj[1]=q4.y; hj[2]=q4.z; hj[3]=q4.w;
        hj[4]=a.trans[nodeJ*3+0]; hj[5]=a.trans[nodeJ*3+1]; hj[6]=a.trans[nodeJ*3+2];
#pragma unroll
        for (int d = 0; d < 22; ++d) hj[7+d] = a.feats[nodeJ*22 + d];
        hj[29] = tval;
        Quat qj = {hj[0], hj[1], hj[2], hj[3]};
        float3 xj = {hj[4], hj[5], hj[6]};

        // Cd_j = h_j @ WmCq
        float cd[6];
#pragma unroll
        for (int dd = 0; dd < 6; ++dd) cd[dd] = 0.f;
#pragma unroll
        for (int d = 0; d < 30; ++d) {
            const float hv = hj[d];
#pragma unroll
            for (int dd = 0; dd < 6; ++dd) cd[dd] = fmaf(hv, sWmCq[d*6+dd], cd[dd]);
        }

        // geometry
        float3 diff = {xi.x - xj.x, xi.y - xj.y, xi.z - xj.z};
        Quat qjc = qconj(qj);
        float3 lx = qrot(qjc, diff);
        Quat lq = qmul(qmul(qjc, qi), qj);
        const float d2v = diff.x*diff.x + diff.y*diff.y + diff.z*diff.z;
        const float dt = fabsf(qi.w*qj.w + qi.x*qj.x + qi.y*qj.y + qi.z*qj.z);
        const float g[9] = {lx.x, lx.y, lx.z, lq.w, lq.x, lq.y, lq.z, d2v, dt};

        // delta = Ad_i + Cd_j + (E row @ Wq) + g.Gq, then *mm
        float delta[6];
#pragma unroll
        for (int dd = 0; dd < 6; ++dd) delta[dd] = sAd[dd] + cd[dd];
        const float* Er = a.wm1 + (60 + (NN-1) + i - j)*32;
#pragma unroll
        for (int k = 0; k < 32; ++k) {
            const float ev = Er[k];
#pragma unroll
            for (int dd = 0; dd < 6; ++dd) delta[dd] = fmaf(ev, sWq[k*6+dd], delta[dd]);
        }
#pragma unroll
        for (int t = 0; t < 9; ++t) {
            const float gv = g[t];
#pragma unroll
            for (int dd = 0; dd < 6; ++dd) delta[dd] = fmaf(gv, sGq[t*6+dd], delta[dd]);
        }
#pragma unroll
        for (int dd = 0; dd < 6; ++dd) delta[dd] *= mm;

#pragma unroll
        for (int t = 0; t < 9; ++t) vals[t] = g[t]*mm;
        float3 dv = {delta[3], delta[4], delta[5]};
        float3 rd = qrot(qj, dv);
        vals[9]  = rd.x; vals[10] = rd.y; vals[11] = rd.z;
        Quat vq = {0.f, delta[0], delta[1], delta[2]};
        Quat sp = qmul(lq, vq);
        vals[12] = lq.w + sp.w;
        vals[13] = lq.x + sp.x;
        vals[14] = lq.y + sp.y;
        vals[15] = lq.z + sp.z;
    }

    // pass V: 16 vals channels
#pragma unroll
    for (int v = 0; v < 16; ++v) sMat[v*STR + tid] = vals[v];
    reduce_pass(sMat, sPr, tid, 16);
    if (tid < 16) sTot[tid] = (sPr[4*tid]+sPr[4*tid+1]) + (sPr[4*tid+2]+sPr[4*tid+3]);
    __syncthreads();

    // pass H1/H2: Hsum over full batch (incl. j==i, no mask)
#pragma unroll
    for (int r = 0; r < 16; ++r) sMat[r*STR + tid] = act ? hj[r] : 0.f;
    reduce_pass(sMat, sPr, tid, 16);
    if (tid < 16) sHsum[tid] = (sPr[4*tid]+sPr[4*tid+1]) + (sPr[4*tid+2]+sPr[4*tid+3]);
    __syncthreads();
#pragma unroll
    for (int r = 0; r < 14; ++r) sMat[r*STR + tid] = act ? hj[16+r] : 0.f;
    reduce_pass(sMat, sPr, tid, 14);
    if (tid < 14) sHsum[16+tid] = (sPr[4*tid]+sPr[4*tid+1]) + (sPr[4*tid+2]+sPr[4*tid+3]);
    __syncthreads();

    // pass E1/E2: Etot = sum over ALL j of E row (149+i-j) (reload, L2-hot)
    {
        const float* ErP = a.wm1 + (60 + (NN-1) + i - j)*32;
#pragma unroll
        for (int r = 0; r < 16; ++r) sMat[r*STR + tid] = act ? ErP[r] : 0.f;
        reduce_pass(sMat, sPr, tid, 16);
        if (tid < 16) sEt[tid] = (sPr[4*tid]+sPr[4*tid+1]) + (sPr[4*tid+2]+sPr[4*tid+3]);
        __syncthreads();
#pragma unroll
        for (int r = 0; r < 16; ++r) sMat[r*STR + tid] = act ? ErP[16+r] : 0.f;
        reduce_pass(sMat, sPr, tid, 16);
        if (tid < 16) sEt[16+tid] = (sPr[4*tid]+sPr[4*tid+1]) + (sPr[4*tid+2]+sPr[4*tid+3]);
        __syncthreads();
    }

    // msum + q/x epilogue
    if (tid < 32) {
        const int k = tid;
        float ms = 149.f*sA[k] - sCi[k] + sEt[k] - a.wm1[(60 + (NN-1))*32 + k];
#pragma unroll
        for (int d = 0; d < 30; ++d) ms = fmaf(sHsum[d], a.wm1[(30+d)*32 + k], ms);
#pragma unroll
        for (int t = 0; t < 9; ++t) ms = fmaf(sTot[t], a.wm1[(60+NE+t)*32 + k], ms);
        sMs[k] = ms;
    }
    if (tid == 64) {
        const float inv = 1.0f / (float)(NN - 1);
        const float ux0 = ((float)NN * xi.x + sTot[9])  * inv;
        const float ux1 = ((float)NN * xi.y + sTot[10]) * inv;
        const float ux2 = ((float)NN * xi.z + sTot[11]) * inv;
        Quat s = {sTot[12], sTot[13], sTot[14], sTot[15]};
        const float nrm = sqrtf(s.w*s.w + s.x*s.x + s.y*s.y + s.z*s.z);
        const float invn = 1.0f / fmaxf(nrm, 1e-12f);
        Quat u = {s.w*invn, s.x*invn, s.y*invn, s.z*invn};
        Quat uq = qmul(qmul(qi, u), qconj(qi));
        a.qout[nodeI*4+0] = uq.w; a.qout[nodeI*4+1] = uq.x;
        a.qout[nodeI*4+2] = uq.y; a.qout[nodeI*4+3] = uq.z;
        a.xout[nodeI*3+0] = ux0;  a.xout[nodeI*3+1] = ux1;
        a.xout[nodeI*3+2] = ux2;
    }
    __syncthreads();

    // o = [h_i, msum] @ Wf1
    if (tid < 64) {
        float acc0 = a.bf1[tid], acc1 = 0.f;
#pragma unroll
        for (int d = 0; d < 30; d += 2) {
            acc0 = fmaf(sHi[d],   a.wf1[d*64 + tid],     acc0);
            acc1 = fmaf(sHi[d+1], a.wf1[(d+1)*64 + tid], acc1);
        }
#pragma unroll
        for (int k = 0; k < 32; k += 2) {
            acc0 = fmaf(sMs[k],   a.wf1[(30+k)*64 + tid],   acc0);
            acc1 = fmaf(sMs[k+1], a.wf1[(30+k+1)*64 + tid], acc1);
        }
        sO[tid] = acc0 + acc1;
    }
    __syncthreads();

    // tail: L2 node work
    if (tid < 64) {
        const float hn = fmaxf(sO[tid], 0.f);
        sH2[tid] = hn;
        a.hout[nodeI*64 + tid] = hn;
    }
    __syncthreads();
    if (tid < 64) {
        const int k   = tid & 31;
        const int off = (tid >= 32) ? 64 : 0;
        float acc = (tid < 32) ? a.bmN[k] : 0.f;
#pragma unroll
        for (int d = 0; d < 64; ++d) acc = fmaf(sH2[d], a.wmN[(off+d)*32 + k], acc);
        if (tid < 32) { sA2[k] = acc; a.Aout[nodeI*32 + k] = acc; }
        else          { sC2[k] = acc; a.Cout[nodeI*32 + k] = acc; }
    }
    __syncthreads();
    if (tid < 12) {
        const int half = (tid >= 6) ? 1 : 0;
        const int dd = tid - half*6;
        const float* src = half ? sC2 : sA2;
        float acc = half ? 0.f : a.bqN[dd];
#pragma unroll
        for (int k = 0; k < 32; ++k) acc = fmaf(src[k], a.wqN[k*6 + dd], acc);
        (half ? a.Cdout : a.Adout)[nodeI*8 + dd] = acc;
    }

    // L2 tables
    const float* EN = a.wmN + 2*64*32;
    if (nodeI < NE && tid >= 64 && tid < 70) {
        const int dd = tid - 64;
        float acc = 0.f;
#pragma unroll
        for (int k = 0; k < 32; ++k) acc = fmaf(EN[nodeI*32+k], a.wqN[k*6+dd], acc);
        a.EdN[nodeI*8+dd] = acc;
    }
    if (nodeI == 1100 && tid >= 64 && tid < 118) {
        const int tt = tid-64; const int tr = tt/6, dd = tt - tr*6;
        float acc = 0.f;
#pragma unroll
        for (int k = 0; k < 32; ++k) acc = fmaf(EN[(NE+tr)*32+k], a.wqN[k*6+dd], acc);
        a.GqN[tr*6+dd] = acc;
    }
    if (nodeI == 1101) {
        __syncthreads();
        const int gp = tid >> 5, k = tid & 31;   // 6 groups x 32 channels
        const int r0 = gp*50;
        float part = 0.f;
        for (int r = r0; r < r0+50 && r < NE; ++r) part += EN[r*32 + k];
        sMat[gp*32 + k] = part;
        __syncthreads();
        float run = 0.f;
        for (int gg = 0; gg < gp; ++gg) run += sMat[gg*32 + k];
        for (int r = r0; r < r0+50; ++r) {
            a.PN[r*32 + k] = run;
            if (r < NE) run += EN[r*32 + k];
        }
    }
}

// ---------------------------------------------------------------------------
// P2..P4: thin pair kernel; C-sum via two extra in-block LDS passes (no
// atomics/zeroing); tables for next layer produced in tail (COMPUTE_O).
// ---------------------------------------------------------------------------
struct PairArgs {
    const float* qcur; const float* xcur;
    const float* hbuf; const float* Abuf; const float* Cin;
    const float* Adin; const float* Cdin;
    const float* Ed; const float* Gq; const float* P;
    const float* wm; const float* wf; const float* bf;
    const float* wmN; const float* bmN; const float* wqN; const float* bqN;
    float* hout; float* Aout; float* Adout; float* Cout; float* Cdout;
    float* PN; float* EdN; float* GqN;
    float* qout; float* xout; float* dout;
};

template<bool COMPUTE_O, bool WRITE_OUT, bool TAIL_FULL>
__global__ __launch_bounds__(192, 4) void pair_kernel(PairArgs a)
{
    constexpr int HD  = 64;
    constexpr int STR = 196;
    constexpr int NV  = COMPUTE_O ? 16 : 7;
    __shared__ __align__(16) float sMat[NV*STR];
    __shared__ float sPr[64];
    __shared__ float sTot[16], sCs[32];
    __shared__ float sHi[64], sO[64], sMs[32];
    __shared__ float sGq[54], sAd[6];
    __shared__ float sA2[32], sC2[32];

    const int tid   = threadIdx.x;
    const int nodeI = blockIdx.x;
    const int b     = nodeI / NN;
    const int i     = nodeI - b*NN;
    const int j     = tid;

    if (COMPUTE_O) { if (tid < HD) sHi[tid] = a.hbuf[nodeI*64 + tid]; }
    if (tid < 54) sGq[tid] = a.Gq[tid];
    if (tid >= 64 && tid < 70) sAd[tid-64] = a.Adin[nodeI*8 + (tid-64)];
    __syncthreads();   // B0

    const float4 qi4 = ((const float4*)a.qcur)[nodeI];
    const Quat  qi = {qi4.x, qi4.y, qi4.z, qi4.w};
    const float3 xi = {a.xcur[nodeI*3+0], a.xcur[nodeI*3+1], a.xcur[nodeI*3+2]};

    const bool act = (j < NN);
    const int nodeJ = b*NN + j;
    const float mm = (j == i) ? 0.f : 1.f;

    float vals[NV];
#pragma unroll
    for (int v = 0; v < NV; ++v) vals[v] = 0.f;

    if (act) {
        const float4 q4 = ((const float4*)a.qcur)[nodeJ];
        Quat qj = {q4.x, q4.y, q4.z, q4.w};
        float3 xj = {a.xcur[nodeJ*3+0], a.xcur[nodeJ*3+1], a.xcur[nodeJ*3+2]};

        float3 diff = {xi.x - xj.x, xi.y - xj.y, xi.z - xj.z};
        Quat qjc = qconj(qj);
        float3 lx = qrot(qjc, diff);
        Quat lq = qmul(qmul(qjc, qi), qj);
        const float d2v = diff.x*diff.x + diff.y*diff.y + diff.z*diff.z;
        const float dt = fabsf(qi.w*qj.w + qi.x*qj.x + qi.y*qj.y + qi.z*qj.z);
        const float g[9] = {lx.x, lx.y, lx.z, lq.w, lq.x, lq.y, lq.z, d2v, dt};

        const float4* cd4 = (const float4*)(a.Cdin + nodeJ*8);
        const float4* ed4 = (const float4*)(a.Ed + (NN-1 + i - j)*8);
        const float4 c0 = cd4[0], c1 = cd4[1];
        const float4 e0 = ed4[0], e1 = ed4[1];
        float delta[6];
        delta[0] = sAd[0] + c0.x + e0.x;
        delta[1] = sAd[1] + c0.y + e0.y;
        delta[2] = sAd[2] + c0.z + e0.z;
        delta[3] = sAd[3] + c0.w + e0.w;
        delta[4] = sAd[4] + c1.x + e1.x;
        delta[5] = sAd[5] + c1.y + e1.y;
#pragma unroll
        for (int t = 0; t < 9; ++t) {
            const float gv = g[t];
#pragma unroll
            for (int dd = 0; dd < 6; ++dd) delta[dd] = fmaf(gv, sGq[t*6 + dd], delta[dd]);
        }
#pragma unroll
        for (int dd = 0; dd < 6; ++dd) delta[dd] *= mm;

        constexpr int vo = COMPUTE_O ? 9 : 0;
        if (COMPUTE_O) {
#pragma unroll
            for (int t = 0; t < 9; ++t) vals[t] = g[t]*mm;
        }
        float3 dv = {delta[3], delta[4], delta[5]};
        float3 rd = qrot(qj, dv);
        vals[vo+0] = rd.x; vals[vo+1] = rd.y; vals[vo+2] = rd.z;
        Quat vq = {0.f, delta[0], delta[1], delta[2]};
        Quat sp = qmul(lq, vq);
        vals[vo+3] = lq.w + sp.w;
        vals[vo+4] = lq.x + sp.x;
        vals[vo+5] = lq.y + sp.y;
        vals[vo+6] = lq.z + sp.z;
    }

    // pass V
#pragma unroll
    for (int v = 0; v < NV; ++v) sMat[v*STR + tid] = vals[v];
    reduce_pass(sMat, sPr, tid, NV);
    if (tid < NV) sTot[tid] = (sPr[4*tid]+sPr[4*tid+1]) + (sPr[4*tid+2]+sPr[4*tid+3]);
    __syncthreads();

    if (COMPUTE_O) {
        // C passes: sum_{j!=i} C_j (masked), 16 channels at a time
        const float4* c4p = (const float4*)(a.Cin + nodeJ*32);
#pragma unroll
        for (int q = 0; q < 4; ++q) {
            float4 c = act ? c4p[q] : float4{0,0,0,0};
            sMat[(4*q+0)*STR + tid] = c.x*mm;
            sMat[(4*q+1)*STR + tid] = c.y*mm;
            sMat[(4*q+2)*STR + tid] = c.z*mm;
            sMat[(4*q+3)*STR + tid] = c.w*mm;
        }
        reduce_pass(sMat, sPr, tid, 16);
        if (tid < 16) sCs[tid] = (sPr[4*tid]+sPr[4*tid+1]) + (sPr[4*tid+2]+sPr[4*tid+3]);
        __syncthreads();
#pragma unroll
        for (int q = 0; q < 4; ++q) {
            float4 c = act ? c4p[4+q] : float4{0,0,0,0};
            sMat[(4*q+0)*STR + tid] = c.x*mm;
            sMat[(4*q+1)*STR + tid] = c.y*mm;
            sMat[(4*q+2)*STR + tid] = c.z*mm;
            sMat[(4*q+3)*STR + tid] = c.w*mm;
        }
        reduce_pass(sMat, sPr, tid, 16);
        if (tid < 16) sCs[16+tid] = (sPr[4*tid]+sPr[4*tid+1]) + (sPr[4*tid+2]+sPr[4*tid+3]);
        __syncthreads();

        // msum + q/x epilogue
        if (tid < 32) {
            const int k = tid;
            float ms = 149.f*a.Abuf[nodeI*32 + k] + sCs[k]
                     + a.P[(i+NN)*32 + k] - a.P[i*32 + k]
                     - a.wm[(2*HD + (NN-1))*32 + k];
#pragma unroll
            for (int t = 0; t < 9; ++t)
                ms = fmaf(sTot[t], a.wm[(2*HD + NE + t)*32 + k], ms);
            sMs[k] = ms;
        }
        if (tid == 64) {
            const float inv = 1.0f / (float)(NN - 1);
            const float ux0 = ((float)NN * xi.x + sTot[9])  * inv;
            const float ux1 = ((float)NN * xi.y + sTot[10]) * inv;
            const float ux2 = ((float)NN * xi.z + sTot[11]) * inv;
            Quat s = {sTot[12], sTot[13], sTot[14], sTot[15]};
            const float nrm = sqrtf(s.w*s.w + s.x*s.x + s.y*s.y + s.z*s.z);
            const float invn = 1.0f / fmaxf(nrm, 1e-12f);
            Quat u = {s.w*invn, s.x*invn, s.y*invn, s.z*invn};
            Quat uq = qmul(qmul(qi, u), qconj(qi));
            a.qout[nodeI*4+0] = uq.w; a.qout[nodeI*4+1] = uq.x;
            a.qout[nodeI*4+2] = uq.y; a.qout[nodeI*4+3] = uq.z;
            a.xout[nodeI*3+0] = ux0;  a.xout[nodeI*3+1] = ux1;
            a.xout[nodeI*3+2] = ux2;
        }
        __syncthreads();

        if (tid < 64) {
            float acc0 = a.bf[tid], acc1 = 0.f;
#pragma unroll 8
            for (int d = 0; d < HD; d += 2) {
                acc0 = fmaf(sHi[d],   a.wf[d*64 + tid],     acc0);
                acc1 = fmaf(sHi[d+1], a.wf[(d+1)*64 + tid], acc1);
            }
#pragma unroll 8
            for (int k = 0; k < 32; k += 2) {
                acc0 = fmaf(sMs[k],   a.wf[(HD+k)*64 + tid],   acc0);
                acc1 = fmaf(sMs[k+1], a.wf[(HD+k+1)*64 + tid], acc1);
            }
            sO[tid] = acc0 + acc1;
        }
        __syncthreads();

        // tail: next layer node work
        if (tid < 64) {
            const float hn = fmaxf(sO[tid], 0.f);
            sHi[tid] = hn;
            if (TAIL_FULL) a.hout[nodeI*64 + tid] = hn;
        }
        __syncthreads();
        if (tid < 64) {
            const int k   = tid & 31;
            const int off = (tid >= 32) ? 64 : 0;
            float acc = (tid < 32) ? a.bmN[k] : 0.f;
#pragma unroll
            for (int d = 0; d < 64; ++d) acc = fmaf(sHi[d], a.wmN[(off+d)*32 + k], acc);
            if (tid < 32) { sA2[k] = acc; if (TAIL_FULL) a.Aout[nodeI*32 + k] = acc; }
            else          { sC2[k] = acc; if (TAIL_FULL) a.Cout[nodeI*32 + k] = acc; }
        }
        __syncthreads();
        if (tid < 12) {
            const int half = (tid >= 6) ? 1 : 0;
            const int dd = tid - half*6;
            const float* src = half ? sC2 : sA2;
            float acc = half ? 0.f : a.bqN[dd];
#pragma unroll
            for (int k = 0; k < 32; ++k) acc = fmaf(src[k], a.wqN[k*6 + dd], acc);
            (half ? a.Cdout : a.Adout)[nodeI*8 + dd] = acc;
        }

        // next-layer tables
        const float* EN = a.wmN + 2*64*32;
        if (nodeI < NE && tid >= 64 && tid < 70) {
            const int dd = tid - 64;
            float acc = 0.f;
#pragma unroll
            for (int k = 0; k < 32; ++k) acc = fmaf(EN[nodeI*32+k], a.wqN[k*6+dd], acc);
            a.EdN[nodeI*8+dd] = acc;
        }
        if (nodeI == 1100 && tid >= 64 && tid < 118) {
            const int tt = tid-64; const int tr = tt/6, dd = tt - tr*6;
            float acc = 0.f;
#pragma unroll
            for (int k = 0; k < 32; ++k) acc = fmaf(EN[(NE+tr)*32+k], a.wqN[k*6+dd], acc);
            a.GqN[tr*6+dd] = acc;
        }
        if (nodeI == 1101) {
            __syncthreads();
            const int gp = tid >> 5, k = tid & 31;
            const int r0 = gp*50;
            float part = 0.f;
            for (int r = r0; r < r0+50 && r < NE; ++r) part += EN[r*32 + k];
            sMat[gp*32 + k] = part;
            __syncthreads();
            float run = 0.f;
            for (int gg = 0; gg < gp; ++gg) run += sMat[gg*32 + k];
            for (int r = r0; r < r0+50; ++r) {
                a.PN[r*32 + k] = run;
                if (r < NE) run += EN[r*32 + k];
            }
        }
    } else {
        if (tid == 0) {
            const float inv = 1.0f / (float)(NN - 1);
            const float ux0 = ((float)NN * xi.x + sTot[0]) * inv;
            const float ux1 = ((float)NN * xi.y + sTot[1]) * inv;
            const float ux2 = ((float)NN * xi.z + sTot[2]) * inv;
            Quat s = {sTot[3], sTot[4], sTot[5], sTot[6]};
            const float nrm = sqrtf(s.w*s.w + s.x*s.x + s.y*s.y + s.z*s.z);
            const float invn = 1.0f / fmaxf(nrm, 1e-12f);
            Quat u = {s.w*invn, s.x*invn, s.y*invn, s.z*invn};
            Quat uq = qmul(qmul(qi, u), qconj(qi));
            if (WRITE_OUT) {
                float* op = a.dout + nodeI*7;
                op[0] = uq.w; op[1] = uq.x; op[2] = uq.y; op[3] = uq.z;
                op[4] = ux0;  op[5] = ux1;  op[6] = ux2;
            } else {
                a.qout[nodeI*4+0] = uq.w; a.qout[nodeI*4+1] = uq.x;
                a.qout[nodeI*4+2] = uq.y; a.qout[nodeI*4+3] = uq.z;
                a.xout[nodeI*3+0] = ux0;  a.xout[nodeI*3+1] = ux1;
                a.xout[nodeI*3+2] = ux2;
            }
        }
    }
}

// ---------------------------------------------------------------------------

extern "C" void kernel_launch(void* const* d_in, const int* in_sizes, int n_in,
                              void* d_out, int out_size, void* d_ws, size_t ws_size,
                              hipStream_t stream) {
    const float* quats = (const float*)d_in[0];
    const float* trans = (const float*)d_in[1];
    const float* wm[4] = {(const float*)d_in[5],  (const float*)d_in[11],
                          (const float*)d_in[17], (const float*)d_in[23]};
    const float* bm[4] = {(const float*)d_in[6],  (const float*)d_in[12],
                          (const float*)d_in[18], (const float*)d_in[24]};
    const float* wf[4] = {(const float*)d_in[7],  (const float*)d_in[13],
                          (const float*)d_in[19], (const float*)d_in[25]};
    const float* bf[4] = {(const float*)d_in[8],  (const float*)d_in[14],
                          (const float*)d_in[20], (const float*)d_in[26]};
    const float* wq[4] = {(const float*)d_in[9],  (const float*)d_in[15],
                          (const float*)d_in[21], (const float*)d_in[27]};
    const float* bq[4] = {(const float*)d_in[10], (const float*)d_in[16],
                          (const float*)d_in[22], (const float*)d_in[28]};

    float* ws = (float*)d_ws;
    float* h   = ws;               // 1200*64
    float* A   = h   + NNODE*64;   // 1200*32
    float* CA  = A   + NNODE*32;   // 1200*32
    float* CB  = CA  + NNODE*32;   // 1200*32
    float* Ad  = CB  + NNODE*32;   // 1200*8
    float* CdA = Ad  + NNODE*8;    // 1200*8
    float* CdB = CdA + NNODE*8;    // 1200*8
    float* qA  = CdB + NNODE*8;    // 1200*4
    float* xA  = qA  + NNODE*4;    // 1200*3
    float* qB  = xA  + NNODE*3;    // 1200*4
    float* xB  = qB  + NNODE*4;    // 1200*3
    float* Pp  = xB  + NNODE*3;    // 4*300*32 (regions 1..3 used)
    float* Edp = Pp  + 4*9600;     // 4*300*8
    float* Gqp = Edp + 4*2400;     // 4*64

    // ---- P1: layer 1 (fully fused, produces L2 data + tables) ----
    Pair1Args p1;
    p1.quats = quats; p1.trans = trans;
    p1.feats = (const float*)d_in[2];
    p1.tptr  = (const int*)d_in[4];
    p1.wm1 = wm[0]; p1.bm1 = bm[0]; p1.wq1 = wq[0]; p1.bq1 = bq[0];
    p1.wf1 = wf[0]; p1.bf1 = bf[0];
    p1.wmN = wm[1]; p1.bmN = bm[1]; p1.wqN = wq[1]; p1.bqN = bq[1];
    p1.hout = h; p1.Aout = A; p1.Adout = Ad; p1.Cout = CA; p1.Cdout = CdA;
    p1.PN = Pp + 1*9600; p1.EdN = Edp + 1*2400; p1.GqN = Gqp + 1*64;
    p1.qout = qA; p1.xout = xA;
    pair1_kernel<<<dim3(NNODE), dim3(192), 0, stream>>>(p1);

    PairArgs p;
    p.dout = (float*)d_out;

    // ---- P2: layer 2 ----
    p.qcur = qA; p.xcur = xA;
    p.hbuf = h; p.Abuf = A; p.Cin = CA; p.Adin = Ad; p.Cdin = CdA;
    p.Ed = Edp + 1*2400; p.Gq = Gqp + 1*64; p.P = Pp + 1*9600;
    p.wm = wm[1]; p.wf = wf[1]; p.bf = bf[1];
    p.wmN = wm[2]; p.bmN = bm[2]; p.wqN = wq[2]; p.bqN = bq[2];
    p.hout = h; p.Aout = A; p.Adout = Ad; p.Cout = CB; p.Cdout = CdB;
    p.PN = Pp + 2*9600; p.EdN = Edp + 2*2400; p.GqN = Gqp + 2*64;
    p.qout = qB; p.xout = xB;
    pair_kernel<true, false, true><<<dim3(NNODE), dim3(192), 0, stream>>>(p);

    // ---- P3: layer 3 (light tail: L4 needs only Ad/Cd + tables) ----
    p.qcur = qB; p.xcur = xB;
    p.Cin = CB; p.Cdin = CdB;
    p.Ed = Edp + 2*2400; p.Gq = Gqp + 2*64; p.P = Pp + 2*9600;
    p.wm = wm[2]; p.wf = wf[2]; p.bf = bf[2];
    p.wmN = wm[3]; p.bmN = bm[3]; p.wqN = wq[3]; p.bqN = bq[3];
    p.Cout = CA; p.Cdout = CdA;
    p.PN = Pp + 3*9600; p.EdN = Edp + 3*2400; p.GqN = Gqp + 3*64;
    p.qout = qA; p.xout = xA;
    pair_kernel<true, false, false><<<dim3(NNODE), dim3(192), 0, stream>>>(p);

    // ---- P4: layer 4 -> d_out ----
    p.qcur = qA; p.xcur = xA;
    p.Cin = CA; p.Cdin = CdA; p.Adin = Ad;
    p.Ed = Edp + 3*2400; p.Gq = Gqp + 3*64; p.P = Pp + 3*9600;
    p.wm = wm[3]; p.wf = wf[3]; p.bf = bf[3];
    p.wmN = wm[3]; p.bmN = bm[3]; p.wqN = wq[3]; p.bqN = bq[3];  // unused
    p.qout = nullptr; p.xout = nullptr;
    pair_kernel<false, true, false><<<dim3(NNODE), dim3(192), 0, stream>>>(p);
}

// Round 9
// 214.153 us; speedup vs baseline: 1.0341x; 1.0341x over previous
//
#include <hip/hip_runtime.h>
#include <math.h>

#define NB 8
#define NN 150
#define NE 299          // 2*N-1
#define NNODE (NB*NN)   // 1200

struct Quat { float w, x, y, z; };

__device__ inline Quat qmul(Quat a, Quat b) {
    Quat r;
    r.w = a.w*b.w - a.x*b.x - a.y*b.y - a.z*b.z;
    r.x = a.w*b.x + a.x*b.w + a.y*b.z - a.z*b.y;
    r.y = a.w*b.y - a.x*b.z + a.y*b.w + a.z*b.x;
    r.z = a.w*b.z + a.x*b.y - a.y*b.x + a.z*b.w;
    return r;
}
__device__ inline Quat qconj(Quat a) { return Quat{a.w, -a.x, -a.y, -a.z}; }

__device__ inline float3 qrot(Quat q, float3 v) {
    float tx = 2.f*(q.y*v.z - q.z*v.y);
    float ty = 2.f*(q.z*v.x - q.x*v.z);
    float tz = 2.f*(q.x*v.y - q.y*v.x);
    float cx = q.y*tz - q.z*ty;
    float cy = q.z*tx - q.x*tz;
    float cz = q.x*ty - q.y*tx;
    float3 r;
    r.x = v.x + q.w*tx + cx;
    r.y = v.y + q.w*ty + cy;
    r.z = v.z + q.w*tz + cz;
    return r;
}

// Single LDS-transpose reduce pass (per-pair values only).
__device__ __forceinline__ void reduce_pass(const float* sMat, float* sPr,
                                            int tid, int nch) {
    __syncthreads();
    if (tid < 4*nch) {
        const int ch = tid >> 2, q4i = tid & 3;
        const float4* row = (const float4*)(sMat + ch*196 + q4i*48);
        float s0=0.f, s1=0.f, s2=0.f, s3=0.f;
#pragma unroll
        for (int it = 0; it < 12; ++it) {
            const float4 r = row[it];
            s0 += r.x; s1 += r.y; s2 += r.z; s3 += r.w;
        }
        sPr[tid] = (s0+s1) + (s2+s3);
    }
    __syncthreads();
}

// ---------------------------------------------------------------------------
// P1: layer 1 fully in-block. Per-pair: Cd_j = h_j @ WmCq, Ed inline.
// Hsum/Etot via strided coalesced global sums (NOT LDS passes).
// msum = 149A_i - C_i + Hsum@WmC + (Etot - E149) + Gsum.WmG.
// Tail: L2 node work + L2 tables (Ed/Gq/P-scan).
// ---------------------------------------------------------------------------
struct Pair1Args {
    const float* quats; const float* trans; const float* feats; const int* tptr;
    const float* wm1; const float* bm1; const float* wq1; const float* bq1;
    const float* wf1; const float* bf1;
    const float* wmN; const float* bmN; const float* wqN; const float* bqN;
    float* hout; float* Aout; float* Adout; float* Cout; float* Cdout;
    float* PN; float* EdN; float* GqN;
    float* qout; float* xout;
};

__global__ __launch_bounds__(192, 4) void pair1_kernel(Pair1Args a)
{
    constexpr int STR = 196;
    __shared__ __align__(16) float sMat[16*STR];
    __shared__ float sPr[64];
    __shared__ float sTot[16], sHsum[30], sEt[32];
    __shared__ float sHi[30], sA[32], sCi[32], sAd[6];
    __shared__ float sWq[192], sWmCq[180], sGq[54];
    __shared__ float sMs[32], sO[64], sH2[64], sA2[32], sC2[32];

    const int tid   = threadIdx.x;
    const int nodeI = blockIdx.x;
    const int b     = nodeI / NN;
    const int i     = nodeI - b*NN;
    const int j     = tid;
    const float tval = (float)a.tptr[0] * (1.0f/1000.0f);

    // stage raw
    sWq[tid] = a.wq1[tid];
    if (tid < 30) {
        float v;
        if      (tid < 4)  v = a.quats[nodeI*4 + tid];
        else if (tid < 7)  v = a.trans[nodeI*3 + (tid-4)];
        else if (tid < 29) v = a.feats[nodeI*22 + (tid-7)];
        else               v = tval;
        sHi[tid] = v;
    }
    __syncthreads();   // B0

    // WmCq = WmC@Wq (30x6), Gq = geomrows@Wq (9x6), A_i/C_i
    if (tid < 180) {
        const int d = tid/6, dd = tid - d*6;
        float acc = 0.f;
#pragma unroll
        for (int k = 0; k < 32; ++k) acc = fmaf(a.wm1[(30+d)*32 + k], sWq[k*6+dd], acc);
        sWmCq[tid] = acc;
    }
    if (tid < 54) {
        const int t = tid/6, dd = tid - t*6;
        float acc = 0.f;
#pragma unroll
        for (int k = 0; k < 32; ++k) acc = fmaf(a.wm1[(60+NE+t)*32 + k], sWq[k*6+dd], acc);
        sGq[tid] = acc;
    }
    if (tid >= 128) {
        const int t2 = tid - 128;
        const int k = t2 & 31;
        const int off = (t2 < 32) ? 0 : 30;
        float acc = (t2 < 32) ? a.bm1[k] : 0.f;
#pragma unroll
        for (int d = 0; d < 30; ++d) acc = fmaf(sHi[d], a.wm1[(off+d)*32 + k], acc);
        if (t2 < 32) sA[k] = acc; else sCi[k] = acc;
    }
    __syncthreads();   // B1
    if (tid < 6) {
        float acc = a.bq1[tid];
#pragma unroll
        for (int k = 0; k < 32; ++k) acc = fmaf(sA[k], sWq[k*6+tid], acc);
        sAd[tid] = acc;
    }
    __syncthreads();   // B2

    // ---- strided partial sums (registers, coalesced, L2-hot) ----
    // Etot partial: thread (ge,ke) sums 25 E rows of channel ke
    float ep = 0.f;
    {
        const int ge = tid >> 5, ke = tid & 31;
        const float* Eb = a.wm1 + (60 + i + ge*25)*32 + ke;
#pragma unroll 5
        for (int r = 0; r < 25; ++r) ep += Eb[r*32];
    }
    // Hsum partial: thread (gh,dh) sums 25 nodes of feature dh (full sum, incl j==i)
    float hp = 0.f;
    if (tid < 180) {
        const int gh = tid/30, dh = tid - gh*30;
        const int jb = b*NN + gh*25;
        if (dh < 4)       { for (int r = 0; r < 25; ++r) hp += a.quats[(jb+r)*4 + dh]; }
        else if (dh < 7)  { for (int r = 0; r < 25; ++r) hp += a.trans[(jb+r)*3 + (dh-4)]; }
        else if (dh < 29) { for (int r = 0; r < 25; ++r) hp += a.feats[(jb+r)*22 + (dh-7)]; }
        else              hp = 25.f*tval;
    }

    const float4 qi4 = ((const float4*)a.quats)[nodeI];
    const Quat  qi = {qi4.x, qi4.y, qi4.z, qi4.w};
    const float3 xi = {sHi[4], sHi[5], sHi[6]};

    const bool act = (j < NN);
    const int nodeJ = b*NN + j;
    const float mm = (j == i) ? 0.f : 1.f;

    float vals[16];
#pragma unroll
    for (int v = 0; v < 16; ++v) vals[v] = 0.f;

    if (act) {
        float hj[30];
        const float4 q4 = ((const float4*)a.quats)[nodeJ];
        hj[0]=q4.x; hj[1]=q4.y; hj[2]=q4.z; hj[3]=q4.w;
        hj[4]=a.trans[nodeJ*3+0]; hj[5]=a.trans[nodeJ*3+1]; hj[6]=a.trans[nodeJ*3+2];
#pragma unroll
        for (int d = 0; d < 22; ++d) hj[7+d] = a.feats[nodeJ*22 + d];
        hj[29] = tval;
        Quat qj = {hj[0], hj[1], hj[2], hj[3]};
        float3 xj = {hj[4], hj[5], hj[6]};

        // Cd_j = h_j @ WmCq
        float cd[6];
#pragma unroll
        for (int dd = 0; dd < 6; ++dd) cd[dd] = 0.f;
#pragma unroll
        for (int d = 0; d < 30; ++d) {
            const float hv = hj[d];
#pragma unroll
            for (int dd = 0; dd < 6; ++dd) cd[dd] = fmaf(hv, sWmCq[d*6+dd], cd[dd]);
        }

        // geometry
        float3 diff = {xi.x - xj.x, xi.y - xj.y, xi.z - xj.z};
        Quat qjc = qconj(qj);
        float3 lx = qrot(qjc, diff);
        Quat lq = qmul(qmul(qjc, qi), qj);
        const float d2v = diff.x*diff.x + diff.y*diff.y + diff.z*diff.z;
        const float dt = fabsf(qi.w*qj.w + qi.x*qj.x + qi.y*qj.y + qi.z*qj.z);
        const float g[9] = {lx.x, lx.y, lx.z, lq.w, lq.x, lq.y, lq.z, d2v, dt};

        // delta = Ad_i + Cd_j + (E row @ Wq) + g.Gq, then *mm
        float delta[6];
#pragma unroll
        for (int dd = 0; dd < 6; ++dd) delta[dd] = sAd[dd] + cd[dd];
        const float* Er = a.wm1 + (60 + (NN-1) + i - j)*32;
#pragma unroll
        for (int k = 0; k < 32; ++k) {
            const float ev = Er[k];
#pragma unroll
            for (int dd = 0; dd < 6; ++dd) delta[dd] = fmaf(ev, sWq[k*6+dd], delta[dd]);
        }
#pragma unroll
        for (int t = 0; t < 9; ++t) {
            const float gv = g[t];
#pragma unroll
            for (int dd = 0; dd < 6; ++dd) delta[dd] = fmaf(gv, sGq[t*6+dd], delta[dd]);
        }
#pragma unroll
        for (int dd = 0; dd < 6; ++dd) delta[dd] *= mm;

#pragma unroll
        for (int t = 0; t < 9; ++t) vals[t] = g[t]*mm;
        float3 dv = {delta[3], delta[4], delta[5]};
        float3 rd = qrot(qj, dv);
        vals[9]  = rd.x; vals[10] = rd.y; vals[11] = rd.z;
        Quat vq = {0.f, delta[0], delta[1], delta[2]};
        Quat sp = qmul(lq, vq);
        vals[12] = lq.w + sp.w;
        vals[13] = lq.x + sp.x;
        vals[14] = lq.y + sp.y;
        vals[15] = lq.z + sp.z;
    }

    // ---- V-pass (the only LDS reduce pass) ----
#pragma unroll
    for (int v = 0; v < 16; ++v) sMat[v*STR + tid] = vals[v];
    reduce_pass(sMat, sPr, tid, 16);
    if (tid < 16) sTot[tid] = (sPr[4*tid]+sPr[4*tid+1]) + (sPr[4*tid+2]+sPr[4*tid+3]);
    __syncthreads();   // sTot ready; sMat free

    // ---- combine strided partials via sMat scratch ----
    sMat[tid] = ep;
    if (tid < 180) sMat[256 + tid] = hp;
    __syncthreads();
    if (tid < 32) {
        sEt[tid] = ((sMat[tid] + sMat[32+tid]) + (sMat[64+tid] + sMat[96+tid]))
                 + (sMat[128+tid] + sMat[160+tid]);
    } else if (tid >= 64 && tid < 94) {
        const int d = tid - 64;
        sHsum[d] = ((sMat[256+d] + sMat[286+d]) + (sMat[316+d] + sMat[346+d]))
                 + (sMat[376+d] + sMat[406+d]);
    } else if (tid == 100) {   // q/x epilogue (reads sTot only)
        const float inv = 1.0f / (float)(NN - 1);
        const float ux0 = ((float)NN * xi.x + sTot[9])  * inv;
        const float ux1 = ((float)NN * xi.y + sTot[10]) * inv;
        const float ux2 = ((float)NN * xi.z + sTot[11]) * inv;
        Quat s = {sTot[12], sTot[13], sTot[14], sTot[15]};
        const float nrm = sqrtf(s.w*s.w + s.x*s.x + s.y*s.y + s.z*s.z);
        const float invn = 1.0f / fmaxf(nrm, 1e-12f);
        Quat u = {s.w*invn, s.x*invn, s.y*invn, s.z*invn};
        Quat uq = qmul(qmul(qi, u), qconj(qi));
        a.qout[nodeI*4+0] = uq.w; a.qout[nodeI*4+1] = uq.x;
        a.qout[nodeI*4+2] = uq.y; a.qout[nodeI*4+3] = uq.z;
        a.xout[nodeI*3+0] = ux0;  a.xout[nodeI*3+1] = ux1;
        a.xout[nodeI*3+2] = ux2;
    }
    __syncthreads();

    // msum
    if (tid < 32) {
        const int k = tid;
        float ms = 149.f*sA[k] - sCi[k] + sEt[k] - a.wm1[(60 + (NN-1))*32 + k];
#pragma unroll
        for (int d = 0; d < 30; ++d) ms = fmaf(sHsum[d], a.wm1[(30+d)*32 + k], ms);
#pragma unroll
        for (int t = 0; t < 9; ++t) ms = fmaf(sTot[t], a.wm1[(60+NE+t)*32 + k], ms);
        sMs[k] = ms;
    }
    __syncthreads();

    // o = [h_i, msum] @ Wf1
    if (tid < 64) {
        float acc0 = a.bf1[tid], acc1 = 0.f;
#pragma unroll
        for (int d = 0; d < 30; d += 2) {
            acc0 = fmaf(sHi[d],   a.wf1[d*64 + tid],     acc0);
            acc1 = fmaf(sHi[d+1], a.wf1[(d+1)*64 + tid], acc1);
        }
#pragma unroll
        for (int k = 0; k < 32; k += 2) {
            acc0 = fmaf(sMs[k],   a.wf1[(30+k)*64 + tid],   acc0);
            acc1 = fmaf(sMs[k+1], a.wf1[(30+k+1)*64 + tid], acc1);
        }
        sO[tid] = acc0 + acc1;
    }
    __syncthreads();

    // tail: L2 node work
    if (tid < 64) {
        const float hn = fmaxf(sO[tid], 0.f);
        sH2[tid] = hn;
        a.hout[nodeI*64 + tid] = hn;
    }
    __syncthreads();
    if (tid < 64) {
        const int k   = tid & 31;
        const int off = (tid >= 32) ? 64 : 0;
        float acc = (tid < 32) ? a.bmN[k] : 0.f;
#pragma unroll
        for (int d = 0; d < 64; ++d) acc = fmaf(sH2[d], a.wmN[(off+d)*32 + k], acc);
        if (tid < 32) { sA2[k] = acc; a.Aout[nodeI*32 + k] = acc; }
        else          { sC2[k] = acc; a.Cout[nodeI*32 + k] = acc; }
    }
    __syncthreads();
    if (tid < 12) {
        const int half = (tid >= 6) ? 1 : 0;
        const int dd = tid - half*6;
        const float* src = half ? sC2 : sA2;
        float acc = half ? 0.f : a.bqN[dd];
#pragma unroll
        for (int k = 0; k < 32; ++k) acc = fmaf(src[k], a.wqN[k*6 + dd], acc);
        (half ? a.Cdout : a.Adout)[nodeI*8 + dd] = acc;
    }

    // L2 tables
    const float* EN = a.wmN + 2*64*32;
    if (nodeI < NE && tid >= 64 && tid < 70) {
        const int dd = tid - 64;
        float acc = 0.f;
#pragma unroll
        for (int k = 0; k < 32; ++k) acc = fmaf(EN[nodeI*32+k], a.wqN[k*6+dd], acc);
        a.EdN[nodeI*8+dd] = acc;
    }
    if (nodeI == 1100 && tid >= 64 && tid < 118) {
        const int tt = tid-64; const int tr = tt/6, dd = tt - tr*6;
        float acc = 0.f;
#pragma unroll
        for (int k = 0; k < 32; ++k) acc = fmaf(EN[(NE+tr)*32+k], a.wqN[k*6+dd], acc);
        a.GqN[tr*6+dd] = acc;
    }
    if (nodeI == 1101) {
        __syncthreads();
        const int gp = tid >> 5, k = tid & 31;
        const int r0 = gp*50;
        float part = 0.f;
        for (int r = r0; r < r0+50 && r < NE; ++r) part += EN[r*32 + k];
        sMat[gp*32 + k] = part;
        __syncthreads();
        float run = 0.f;
        for (int gg = 0; gg < gp; ++gg) run += sMat[gg*32 + k];
        for (int r = r0; r < r0+50; ++r) {
            a.PN[r*32 + k] = run;
            if (r < NE) run += EN[r*32 + k];
        }
    }
}

// ---------------------------------------------------------------------------
// P2..P4: thin pair kernel. One V-pass; ΣC via strided coalesced global sum
// (no atomics, no memset); tables for next layer in tail (COMPUTE_O).
// ---------------------------------------------------------------------------
struct PairArgs {
    const float* qcur; const float* xcur;
    const float* hbuf; const float* Abuf; const float* Cin;
    const float* Adin; const float* Cdin;
    const float* Ed; const float* Gq; const float* P;
    const float* wm; const float* wf; const float* bf;
    const float* wmN; const float* bmN; const float* wqN; const float* bqN;
    float* hout; float* Aout; float* Adout; float* Cout; float* Cdout;
    float* PN; float* EdN; float* GqN;
    float* qout; float* xout; float* dout;
};

template<bool COMPUTE_O, bool WRITE_OUT, bool TAIL_FULL>
__global__ __launch_bounds__(192, 4) void pair_kernel(PairArgs a)
{
    constexpr int HD  = 64;
    constexpr int STR = 196;
    constexpr int NV  = COMPUTE_O ? 16 : 7;
    __shared__ __align__(16) float sMat[NV*STR];
    __shared__ float sPr[64];
    __shared__ float sTot[16];
    __shared__ float sHi[64], sO[64], sMs[32];
    __shared__ float sGq[54], sAd[6];
    __shared__ float sA2[32], sC2[32];

    const int tid   = threadIdx.x;
    const int nodeI = blockIdx.x;
    const int b     = nodeI / NN;
    const int i     = nodeI - b*NN;
    const int j     = tid;

    if (COMPUTE_O) { if (tid < HD) sHi[tid] = a.hbuf[nodeI*64 + tid]; }
    if (tid < 54) sGq[tid] = a.Gq[tid];
    if (tid >= 64 && tid < 70) sAd[tid-64] = a.Adin[nodeI*8 + (tid-64)];
    __syncthreads();   // B0

    // strided C partial (coalesced, L2-hot)
    float cp = 0.f;
    if (COMPUTE_O) {
        const int gc = tid >> 5, kc = tid & 31;
        const float* Cb = a.Cin + (b*NN + gc*25)*32 + kc;
#pragma unroll 5
        for (int r = 0; r < 25; ++r) cp += Cb[r*32];
    }

    const float4 qi4 = ((const float4*)a.qcur)[nodeI];
    const Quat  qi = {qi4.x, qi4.y, qi4.z, qi4.w};
    const float3 xi = {a.xcur[nodeI*3+0], a.xcur[nodeI*3+1], a.xcur[nodeI*3+2]};

    const bool act = (j < NN);
    const int nodeJ = b*NN + j;
    const float mm = (j == i) ? 0.f : 1.f;

    float vals[NV];
#pragma unroll
    for (int v = 0; v < NV; ++v) vals[v] = 0.f;

    if (act) {
        const float4 q4 = ((const float4*)a.qcur)[nodeJ];
        Quat qj = {q4.x, q4.y, q4.z, q4.w};
        float3 xj = {a.xcur[nodeJ*3+0], a.xcur[nodeJ*3+1], a.xcur[nodeJ*3+2]};

        float3 diff = {xi.x - xj.x, xi.y - xj.y, xi.z - xj.z};
        Quat qjc = qconj(qj);
        float3 lx = qrot(qjc, diff);
        Quat lq = qmul(qmul(qjc, qi), qj);
        const float d2v = diff.x*diff.x + diff.y*diff.y + diff.z*diff.z;
        const float dt = fabsf(qi.w*qj.w + qi.x*qj.x + qi.y*qj.y + qi.z*qj.z);
        const float g[9] = {lx.x, lx.y, lx.z, lq.w, lq.x, lq.y, lq.z, d2v, dt};

        const float4* cd4 = (const float4*)(a.Cdin + nodeJ*8);
        const float4* ed4 = (const float4*)(a.Ed + (NN-1 + i - j)*8);
        const float4 c0 = cd4[0], c1 = cd4[1];
        const float4 e0 = ed4[0], e1 = ed4[1];
        float delta[6];
        delta[0] = sAd[0] + c0.x + e0.x;
        delta[1] = sAd[1] + c0.y + e0.y;
        delta[2] = sAd[2] + c0.z + e0.z;
        delta[3] = sAd[3] + c0.w + e0.w;
        delta[4] = sAd[4] + c1.x + e1.x;
        delta[5] = sAd[5] + c1.y + e1.y;
#pragma unroll
        for (int t = 0; t < 9; ++t) {
            const float gv = g[t];
#pragma unroll
            for (int dd = 0; dd < 6; ++dd) delta[dd] = fmaf(gv, sGq[t*6 + dd], delta[dd]);
        }
#pragma unroll
        for (int dd = 0; dd < 6; ++dd) delta[dd] *= mm;

        constexpr int vo = COMPUTE_O ? 9 : 0;
        if (COMPUTE_O) {
#pragma unroll
            for (int t = 0; t < 9; ++t) vals[t] = g[t]*mm;
        }
        float3 dv = {delta[3], delta[4], delta[5]};
        float3 rd = qrot(qj, dv);
        vals[vo+0] = rd.x; vals[vo+1] = rd.y; vals[vo+2] = rd.z;
        Quat vq = {0.f, delta[0], delta[1], delta[2]};
        Quat sp = qmul(lq, vq);
        vals[vo+3] = lq.w + sp.w;
        vals[vo+4] = lq.x + sp.x;
        vals[vo+5] = lq.y + sp.y;
        vals[vo+6] = lq.z + sp.z;
    }

    // V-pass (the only LDS reduce pass)
#pragma unroll
    for (int v = 0; v < NV; ++v) sMat[v*STR + tid] = vals[v];
    reduce_pass(sMat, sPr, tid, NV);
    if (tid < NV) sTot[tid] = (sPr[4*tid]+sPr[4*tid+1]) + (sPr[4*tid+2]+sPr[4*tid+3]);
    __syncthreads();

    if (COMPUTE_O) {
        // combine C partials via sMat scratch
        sMat[tid] = cp;
        __syncthreads();
        if (tid < 32) {
            const int k = tid;
            const float csum = ((sMat[k] + sMat[32+k]) + (sMat[64+k] + sMat[96+k]))
                             + (sMat[128+k] + sMat[160+k]);
            float ms = 149.f*a.Abuf[nodeI*32 + k] + csum - a.Cin[nodeI*32 + k]
                     + a.P[(i+NN)*32 + k] - a.P[i*32 + k]
                     - a.wm[(2*HD + (NN-1))*32 + k];
#pragma unroll
            for (int t = 0; t < 9; ++t)
                ms = fmaf(sTot[t], a.wm[(2*HD + NE + t)*32 + k], ms);
            sMs[k] = ms;
        }
        if (tid == 64) {
            const float inv = 1.0f / (float)(NN - 1);
            const float ux0 = ((float)NN * xi.x + sTot[9])  * inv;
            const float ux1 = ((float)NN * xi.y + sTot[10]) * inv;
            const float ux2 = ((float)NN * xi.z + sTot[11]) * inv;
            Quat s = {sTot[12], sTot[13], sTot[14], sTot[15]};
            const float nrm = sqrtf(s.w*s.w + s.x*s.x + s.y*s.y + s.z*s.z);
            const float invn = 1.0f / fmaxf(nrm, 1e-12f);
            Quat u = {s.w*invn, s.x*invn, s.y*invn, s.z*invn};
            Quat uq = qmul(qmul(qi, u), qconj(qi));
            a.qout[nodeI*4+0] = uq.w; a.qout[nodeI*4+1] = uq.x;
            a.qout[nodeI*4+2] = uq.y; a.qout[nodeI*4+3] = uq.z;
            a.xout[nodeI*3+0] = ux0;  a.xout[nodeI*3+1] = ux1;
            a.xout[nodeI*3+2] = ux2;
        }
        __syncthreads();

        if (tid < 64) {
            float acc0 = a.bf[tid], acc1 = 0.f;
#pragma unroll 8
            for (int d = 0; d < HD; d += 2) {
                acc0 = fmaf(sHi[d],   a.wf[d*64 + tid],     acc0);
                acc1 = fmaf(sHi[d+1], a.wf[(d+1)*64 + tid], acc1);
            }
#pragma unroll 8
            for (int k = 0; k < 32; k += 2) {
                acc0 = fmaf(sMs[k],   a.wf[(HD+k)*64 + tid],   acc0);
                acc1 = fmaf(sMs[k+1], a.wf[(HD+k+1)*64 + tid], acc1);
            }
            sO[tid] = acc0 + acc1;
        }
        __syncthreads();

        // tail: next layer node work
        if (tid < 64) {
            const float hn = fmaxf(sO[tid], 0.f);
            sHi[tid] = hn;
            if (TAIL_FULL) a.hout[nodeI*64 + tid] = hn;
        }
        __syncthreads();
        if (tid < 64) {
            const int k   = tid & 31;
            const int off = (tid >= 32) ? 64 : 0;
            float acc = (tid < 32) ? a.bmN[k] : 0.f;
#pragma unroll
            for (int d = 0; d < 64; ++d) acc = fmaf(sHi[d], a.wmN[(off+d)*32 + k], acc);
            if (tid < 32) { sA2[k] = acc; if (TAIL_FULL) a.Aout[nodeI*32 + k] = acc; }
            else          { sC2[k] = acc; if (TAIL_FULL) a.Cout[nodeI*32 + k] = acc; }
        }
        __syncthreads();
        if (tid < 12) {
            const int half = (tid >= 6) ? 1 : 0;
            const int dd = tid - half*6;
            const float* src = half ? sC2 : sA2;
            float acc = half ? 0.f : a.bqN[dd];
#pragma unroll
            for (int k = 0; k < 32; ++k) acc = fmaf(src[k], a.wqN[k*6 + dd], acc);
            (half ? a.Cdout : a.Adout)[nodeI*8 + dd] = acc;
        }

        // next-layer tables
        const float* EN = a.wmN + 2*64*32;
        if (nodeI < NE && tid >= 64 && tid < 70) {
            const int dd = tid - 64;
            float acc = 0.f;
#pragma unroll
            for (int k = 0; k < 32; ++k) acc = fmaf(EN[nodeI*32+k], a.wqN[k*6+dd], acc);
            a.EdN[nodeI*8+dd] = acc;
        }
        if (nodeI == 1100 && tid >= 64 && tid < 118) {
            const int tt = tid-64; const int tr = tt/6, dd = tt - tr*6;
            float acc = 0.f;
#pragma unroll
            for (int k = 0; k < 32; ++k) acc = fmaf(EN[(NE+tr)*32+k], a.wqN[k*6+dd], acc);
            a.GqN[tr*6+dd] = acc;
        }
        if (nodeI == 1101) {
            __syncthreads();
            const int gp = tid >> 5, k = tid & 31;
            const int r0 = gp*50;
            float part = 0.f;
            for (int r = r0; r < r0+50 && r < NE; ++r) part += EN[r*32 + k];
            sMat[gp*32 + k] = part;
            __syncthreads();
            float run = 0.f;
            for (int gg = 0; gg < gp; ++gg) run += sMat[gg*32 + k];
            for (int r = r0; r < r0+50; ++r) {
                a.PN[r*32 + k] = run;
                if (r < NE) run += EN[r*32 + k];
            }
        }
    } else {
        if (tid == 0) {
            const float inv = 1.0f / (float)(NN - 1);
            const float ux0 = ((float)NN * xi.x + sTot[0]) * inv;
            const float ux1 = ((float)NN * xi.y + sTot[1]) * inv;
            const float ux2 = ((float)NN * xi.z + sTot[2]) * inv;
            Quat s = {sTot[3], sTot[4], sTot[5], sTot[6]};
            const float nrm = sqrtf(s.w*s.w + s.x*s.x + s.y*s.y + s.z*s.z);
            const float invn = 1.0f / fmaxf(nrm, 1e-12f);
            Quat u = {s.w*invn, s.x*invn, s.y*invn, s.z*invn};
            Quat uq = qmul(qmul(qi, u), qconj(qi));
            if (WRITE_OUT) {
                float* op = a.dout + nodeI*7;
                op[0] = uq.w; op[1] = uq.x; op[2] = uq.y; op[3] = uq.z;
                op[4] = ux0;  op[5] = ux1;  op[6] = ux2;
            } else {
                a.qout[nodeI*4+0] = uq.w; a.qout[nodeI*4+1] = uq.x;
                a.qout[nodeI*4+2] = uq.y; a.qout[nodeI*4+3] = uq.z;
                a.xout[nodeI*3+0] = ux0;  a.xout[nodeI*3+1] = ux1;
                a.xout[nodeI*3+2] = ux2;
            }
        }
    }
}

// ---------------------------------------------------------------------------

extern "C" void kernel_launch(void* const* d_in, const int* in_sizes, int n_in,
                              void* d_out, int out_size, void* d_ws, size_t ws_size,
                              hipStream_t stream) {
    const float* quats = (const float*)d_in[0];
    const float* trans = (const float*)d_in[1];
    const float* wm[4] = {(const float*)d_in[5],  (const float*)d_in[11],
                          (const float*)d_in[17], (const float*)d_in[23]};
    const float* bm[4] = {(const float*)d_in[6],  (const float*)d_in[12],
                          (const float*)d_in[18], (const float*)d_in[24]};
    const float* wf[4] = {(const float*)d_in[7],  (const float*)d_in[13],
                          (const float*)d_in[19], (const float*)d_in[25]};
    const float* bf[4] = {(const float*)d_in[8],  (const float*)d_in[14],
                          (const float*)d_in[20], (const float*)d_in[26]};
    const float* wq[4] = {(const float*)d_in[9],  (const float*)d_in[15],
                          (const float*)d_in[21], (const float*)d_in[27]};
    const float* bq[4] = {(const float*)d_in[10], (const float*)d_in[16],
                          (const float*)d_in[22], (const float*)d_in[28]};

    float* ws = (float*)d_ws;
    float* h   = ws;               // 1200*64
    float* A   = h   + NNODE*64;   // 1200*32
    float* CA  = A   + NNODE*32;   // 1200*32
    float* CB  = CA  + NNODE*32;   // 1200*32
    float* Ad  = CB  + NNODE*32;   // 1200*8
    float* CdA = Ad  + NNODE*8;    // 1200*8
    float* CdB = CdA + NNODE*8;    // 1200*8
    float* qA  = CdB + NNODE*8;    // 1200*4
    float* xA  = qA  + NNODE*4;    // 1200*3
    float* qB  = xA  + NNODE*3;    // 1200*4
    float* xB  = qB  + NNODE*4;    // 1200*3
    float* Pp  = xB  + NNODE*3;    // 4*300*32 (regions 1..3 used)
    float* Edp = Pp  + 4*9600;     // 4*300*8
    float* Gqp = Edp + 4*2400;     // 4*64

    // ---- P1: layer 1 fused; produces L2 node data + tables ----
    Pair1Args p1;
    p1.quats = quats; p1.trans = trans;
    p1.feats = (const float*)d_in[2];
    p1.tptr  = (const int*)d_in[4];
    p1.wm1 = wm[0]; p1.bm1 = bm[0]; p1.wq1 = wq[0]; p1.bq1 = bq[0];
    p1.wf1 = wf[0]; p1.bf1 = bf[0];
    p1.wmN = wm[1]; p1.bmN = bm[1]; p1.wqN = wq[1]; p1.bqN = bq[1];
    p1.hout = h; p1.Aout = A; p1.Adout = Ad; p1.Cout = CA; p1.Cdout = CdA;
    p1.PN = Pp + 1*9600; p1.EdN = Edp + 1*2400; p1.GqN = Gqp + 1*64;
    p1.qout = qA; p1.xout = xA;
    pair1_kernel<<<dim3(NNODE), dim3(192), 0, stream>>>(p1);

    PairArgs p;
    p.dout = (float*)d_out;

    // ---- P2: layer 2 ----
    p.qcur = qA; p.xcur = xA;
    p.hbuf = h; p.Abuf = A; p.Cin = CA; p.Adin = Ad; p.Cdin = CdA;
    p.Ed = Edp + 1*2400; p.Gq = Gqp + 1*64; p.P = Pp + 1*9600;
    p.wm = wm[1]; p.wf = wf[1]; p.bf = bf[1];
    p.wmN = wm[2]; p.bmN = bm[2]; p.wqN = wq[2]; p.bqN = bq[2];
    p.hout = h; p.Aout = A; p.Adout = Ad; p.Cout = CB; p.Cdout = CdB;
    p.PN = Pp + 2*9600; p.EdN = Edp + 2*2400; p.GqN = Gqp + 2*64;
    p.qout = qB; p.xout = xB;
    pair_kernel<true, false, true><<<dim3(NNODE), dim3(192), 0, stream>>>(p);

    // ---- P3: layer 3 (light tail: L4 needs only Ad/Cd + tables) ----
    p.qcur = qB; p.xcur = xB;
    p.Cin = CB; p.Cdin = CdB;
    p.Ed = Edp + 2*2400; p.Gq = Gqp + 2*64; p.P = Pp + 2*9600;
    p.wm = wm[2]; p.wf = wf[2]; p.bf = bf[2];
    p.wmN = wm[3]; p.bmN = bm[3]; p.wqN = wq[3]; p.bqN = bq[3];
    p.Cout = CA; p.Cdout = CdA;
    p.PN = Pp + 3*9600; p.EdN = Edp + 3*2400; p.GqN = Gqp + 3*64;
    p.qout = qA; p.xout = xA;
    pair_kernel<true, false, false><<<dim3(NNODE), dim3(192), 0, stream>>>(p);

    // ---- P4: layer 4 -> d_out ----
    p.qcur = qA; p.xcur = xA;
    p.Cin = CA; p.Cdin = CdA; p.Adin = Ad;
    p.Ed = Edp + 3*2400; p.Gq = Gqp + 3*64; p.P = Pp + 3*9600;
    p.wm = wm[3]; p.wf = wf[3]; p.bf = bf[3];
    p.wmN = wm[3]; p.bmN = bm[3]; p.wqN = wq[3]; p.bqN = bq[3];  // unused
    p.qout = nullptr; p.xout = nullptr;
    pair_kernel<false, true, false><<<dim3(NNODE), dim3(192), 0, stream>>>(p);
}